// Round 1
// baseline (1289.321 us; speedup 1.0000x reference)
//
#include <hip/hip_runtime.h>

// Darcy flow graph PDE residual:
//   dx,dy  = scatter-mean over valid edges of (x[src]-x[dst])/attr
//   tmp    = a_x * [dx,dy]
//   dxx,dyy= scatter-mean over valid edges of (tmp[src]-tmp[dst])/attr
//   out    = (dxx + dyy + 1) * (1-mask)
//
// Workspace layout (floats): [sum0][sum1][cnt0][cnt1][sum2][sum3][tmp0][tmp1]
// First 6*N floats are zeroed each launch via hipMemsetAsync (capture-safe).

#define BLK 256

__global__ __launch_bounds__(BLK) void edge_pass1(
    const int* __restrict__ eidx,        // [2*E]: src then dst
    const float2* __restrict__ attr,     // [E] float2
    const float* __restrict__ x,         // [N]
    float* __restrict__ sum0, float* __restrict__ sum1,
    float* __restrict__ cnt0, float* __restrict__ cnt1,
    int E)
{
    int e = blockIdx.x * BLK + threadIdx.x;
    if (e >= E) return;
    int s = eidx[e];
    int d = eidx[E + e];
    float2 a = attr[e];
    float diff = x[s] - x[d];
    if (a.x != 0.0f) {
        atomicAdd(&sum0[d], diff / a.x);
        atomicAdd(&cnt0[d], 1.0f);
    }
    if (a.y != 0.0f) {
        atomicAdd(&sum1[d], diff / a.y);
        atomicAdd(&cnt1[d], 1.0f);
    }
}

__global__ __launch_bounds__(BLK) void node_pass1(
    const float* __restrict__ sum0, const float* __restrict__ sum1,
    const float* __restrict__ cnt0, const float* __restrict__ cnt1,
    const float* __restrict__ a_x,
    float* __restrict__ tmp0, float* __restrict__ tmp1,
    int N)
{
    int i = blockIdx.x * BLK + threadIdx.x;
    if (i >= N) return;
    float a = a_x[i];
    tmp0[i] = a * (sum0[i] / fmaxf(cnt0[i], 1.0f));
    tmp1[i] = a * (sum1[i] / fmaxf(cnt1[i], 1.0f));
}

__global__ __launch_bounds__(BLK) void edge_pass2(
    const int* __restrict__ eidx,
    const float2* __restrict__ attr,
    const float* __restrict__ tmp0, const float* __restrict__ tmp1,
    float* __restrict__ sum2, float* __restrict__ sum3,
    int E)
{
    int e = blockIdx.x * BLK + threadIdx.x;
    if (e >= E) return;
    int s = eidx[e];
    int d = eidx[E + e];
    float2 a = attr[e];
    if (a.x != 0.0f) {
        atomicAdd(&sum2[d], (tmp0[s] - tmp0[d]) / a.x);
    }
    if (a.y != 0.0f) {
        atomicAdd(&sum3[d], (tmp1[s] - tmp1[d]) / a.y);
    }
}

__global__ __launch_bounds__(BLK) void node_pass2(
    const float* __restrict__ sum2, const float* __restrict__ sum3,
    const float* __restrict__ cnt0, const float* __restrict__ cnt1,
    const int* __restrict__ mask,
    float* __restrict__ out,
    int N)
{
    int i = blockIdx.x * BLK + threadIdx.x;
    if (i >= N) return;
    float dxx = sum2[i] / fmaxf(cnt0[i], 1.0f);
    float dyy = sum3[i] / fmaxf(cnt1[i], 1.0f);
    float v = dxx + dyy + 1.0f;
    out[i] = v * (1.0f - (float)mask[i]);
}

extern "C" void kernel_launch(void* const* d_in, const int* in_sizes, int n_in,
                              void* d_out, int out_size, void* d_ws, size_t ws_size,
                              hipStream_t stream)
{
    const float* x    = (const float*)d_in[0];
    const float* a_x  = (const float*)d_in[1];
    const int*   eidx = (const int*)d_in[2];
    const float* attr = (const float*)d_in[3];
    const int*   mask = (const int*)d_in[4];
    float* out = (float*)d_out;

    const int N = in_sizes[0];          // x has N elements
    const int E = in_sizes[2] / 2;      // edge_index is [2,E]

    float* ws   = (float*)d_ws;
    float* sum0 = ws + (size_t)0 * N;
    float* sum1 = ws + (size_t)1 * N;
    float* cnt0 = ws + (size_t)2 * N;
    float* cnt1 = ws + (size_t)3 * N;
    float* sum2 = ws + (size_t)4 * N;
    float* sum3 = ws + (size_t)5 * N;
    float* tmp0 = ws + (size_t)6 * N;
    float* tmp1 = ws + (size_t)7 * N;

    // Zero the 6 accumulator arrays (capture-safe async memset).
    hipMemsetAsync(d_ws, 0, (size_t)6 * N * sizeof(float), stream);

    const int egrid = (E + BLK - 1) / BLK;
    const int ngrid = (N + BLK - 1) / BLK;

    edge_pass1<<<egrid, BLK, 0, stream>>>(eidx, (const float2*)attr, x,
                                          sum0, sum1, cnt0, cnt1, E);
    node_pass1<<<ngrid, BLK, 0, stream>>>(sum0, sum1, cnt0, cnt1, a_x,
                                          tmp0, tmp1, N);
    edge_pass2<<<egrid, BLK, 0, stream>>>(eidx, (const float2*)attr,
                                          tmp0, tmp1, sum2, sum3, E);
    node_pass2<<<ngrid, BLK, 0, stream>>>(sum2, sum3, cnt0, cnt1, mask,
                                          out, N);
}